// Round 1
// baseline (1742.528 us; speedup 1.0000x reference)
//
#include <hip/hip_runtime.h>
#include <hip/hip_bf16.h>

// Problem constants (inputs fixed by harness: text [64,512] f32, spots [500000,512] f32, top_k=10)
#define B_TEXT 64
#define D_DIM  512
#define TOPK   10
#define TILE_N 128           // spot rows per block in GEMM
#define BK     64            // K-chunk
#define LDA    (BK + 8)      // LDS leading dim pad (+8 bf16 = 16B, keeps 16B alignment, breaks bank stride)
#define CH     16            // top-k chunks per text row

typedef short bf16x8 __attribute__((ext_vector_type(8)));
typedef float f32x4  __attribute__((ext_vector_type(4)));

__device__ __forceinline__ unsigned short f2bf(float x) {
    unsigned u = __float_as_uint(x);
    u += 0x7fffu + ((u >> 16) & 1u);          // RNE
    return (unsigned short)(u >> 16);
}
__device__ __forceinline__ float bf2f(unsigned short h) {
    return __uint_as_float(((unsigned)h) << 16);
}

// ---------------- K1: normalize text rows, split into bf16 hi/lo ----------------
__global__ void prep_text(const float* __restrict__ T, unsigned short* __restrict__ tHi,
                          unsigned short* __restrict__ tLo) {
    int b = blockIdx.x;
    int lane = threadIdx.x;                    // 64 threads = 1 wave
    const float* row = T + b * D_DIM;
    float4 a = *(const float4*)(row + lane * 4);
    float4 c = *(const float4*)(row + 256 + lane * 4);
    float p = a.x*a.x + a.y*a.y + a.z*a.z + a.w*a.w
            + c.x*c.x + c.y*c.y + c.z*c.z + c.w*c.w;
    #pragma unroll
    for (int off = 1; off < 64; off <<= 1) p += __shfl_xor(p, off);
    float inv = 1.0f / fmaxf(sqrtf(p), 1e-12f);
    float v[8] = {a.x, a.y, a.z, a.w, c.x, c.y, c.z, c.w};
    #pragma unroll
    for (int j = 0; j < 8; ++j) {
        float y = v[j] * inv;
        unsigned short hi = f2bf(y);
        unsigned short lo = f2bf(y - bf2f(hi));   // x - bf16(x) is exact in f32
        int col = (j < 4) ? (lane * 4 + j) : (256 + lane * 4 + (j - 4));
        tHi[b * D_DIM + col] = hi;
        tLo[b * D_DIM + col] = lo;
    }
}

// ---------------- K2: scores = (unit text) . spots^T / ||spot||, split-bf16 MFMA ----------------
// Tile: 64(m) x 128(n), K chunked by 64. 4 waves, wave w owns n in [w*32, w*32+32).
// Fragment layouts per verified m91/m97: A[m=lane&15][k=quad*8+j]; B[n=lane&15][k=quad*8+j];
// C/D: col(n)=lane&15, row(m)=quad*4+reg.
__global__ __launch_bounds__(256, 2) void gemm_scores(
    const float* __restrict__ S, const unsigned short* __restrict__ tHi,
    const unsigned short* __restrict__ tLo, float* __restrict__ out, int N) {

    __shared__ unsigned short As_hi[B_TEXT][LDA];
    __shared__ unsigned short As_lo[B_TEXT][LDA];
    __shared__ unsigned short Bs_hi[TILE_N][LDA];
    __shared__ unsigned short Bs_lo[TILE_N][LDA];
    __shared__ float s_ss[TILE_N];             // per-spot-row sum of squares

    const int tid  = threadIdx.x;
    const int n0   = blockIdx.x * TILE_N;
    const int lane = tid & 63;
    const int w    = tid >> 6;
    const int l15  = lane & 15;
    const int quad = lane >> 4;

    if (tid < TILE_N) s_ss[tid] = 0.0f;

    f32x4 acc[4][2];
    const f32x4 zf = {0.f, 0.f, 0.f, 0.f};
    #pragma unroll
    for (int i = 0; i < 4; ++i)
        #pragma unroll
        for (int j = 0; j < 2; ++j) acc[i][j] = zf;

    const int arow = tid >> 2;                 // A staging: thread -> text row, 16 bf16 per matrix
    const int akq  = (tid & 3) << 4;

    for (int kc = 0; kc < D_DIM; kc += BK) {
        __syncthreads();
        // ---- stage A chunk (pre-split bf16 hi/lo, L2-resident) ----
        {
            const uint4* ph = (const uint4*)(tHi + arow * D_DIM + kc + akq);
            const uint4* pl = (const uint4*)(tLo + arow * D_DIM + kc + akq);
            uint4 h0 = ph[0], h1 = ph[1];
            uint4 l0 = pl[0], l1 = pl[1];
            *(uint4*)&As_hi[arow][akq]     = h0;
            *(uint4*)&As_hi[arow][akq + 8] = h1;
            *(uint4*)&As_lo[arow][akq]     = l0;
            *(uint4*)&As_lo[arow][akq + 8] = l1;
        }
        // ---- stage B chunk: f32 load, hi/lo split, fused sumsq ----
        #pragma unroll
        for (int i = 0; i < 8; ++i) {
            int flat = i * 1024 + tid * 4;     // [128][64] chunk, 16 consecutive threads = 1 row
            int r = flat >> 6;
            int k = flat & 63;
            float4 v;
            if (n0 + r < N) v = *(const float4*)(S + (size_t)(n0 + r) * D_DIM + kc + k);
            else            v = make_float4(0.f, 0.f, 0.f, 0.f);
            ushort4 h, l;
            h.x = f2bf(v.x); l.x = f2bf(v.x - bf2f(h.x));
            h.y = f2bf(v.y); l.y = f2bf(v.y - bf2f(h.y));
            h.z = f2bf(v.z); l.z = f2bf(v.z - bf2f(h.z));
            h.w = f2bf(v.w); l.w = f2bf(v.w - bf2f(h.w));
            *(ushort4*)&Bs_hi[r][k] = h;
            *(ushort4*)&Bs_lo[r][k] = l;
            float p = v.x*v.x + v.y*v.y + v.z*v.z + v.w*v.w;
            p += __shfl_xor(p, 1);
            p += __shfl_xor(p, 2);
            p += __shfl_xor(p, 4);
            p += __shfl_xor(p, 8);
            if ((tid & 15) == 0) s_ss[r] += p; // unique writer per r, same thread every chunk
        }
        __syncthreads();
        // ---- MFMA: acc += hi*hi + hi*lo + lo*hi (split-f32 precision) ----
        #pragma unroll
        for (int ks = 0; ks < 2; ++ks) {
            const int off = ks * 32 + quad * 8;
            bf16x8 ah[4], al[4], bh[2], bl[2];
            #pragma unroll
            for (int mt = 0; mt < 4; ++mt) {
                int m = mt * 16 + l15;
                ah[mt] = *(const bf16x8*)&As_hi[m][off];
                al[mt] = *(const bf16x8*)&As_lo[m][off];
            }
            #pragma unroll
            for (int nt = 0; nt < 2; ++nt) {
                int nl = w * 32 + nt * 16 + l15;
                bh[nt] = *(const bf16x8*)&Bs_hi[nl][off];
                bl[nt] = *(const bf16x8*)&Bs_lo[nl][off];
            }
            #pragma unroll
            for (int mt = 0; mt < 4; ++mt)
                #pragma unroll
                for (int nt = 0; nt < 2; ++nt) {
                    acc[mt][nt] = __builtin_amdgcn_mfma_f32_16x16x32_bf16(ah[mt], bh[nt], acc[mt][nt], 0, 0, 0);
                    acc[mt][nt] = __builtin_amdgcn_mfma_f32_16x16x32_bf16(ah[mt], bl[nt], acc[mt][nt], 0, 0, 0);
                    acc[mt][nt] = __builtin_amdgcn_mfma_f32_16x16x32_bf16(al[mt], bh[nt], acc[mt][nt], 0, 0, 0);
                }
        }
    }
    __syncthreads();
    // ---- epilogue: scale by 1/max(||s||,eps), store ----
    #pragma unroll
    for (int nt = 0; nt < 2; ++nt) {
        int nl = w * 32 + nt * 16 + l15;
        int n  = n0 + nl;
        if (n >= N) continue;
        float inv = 1.0f / fmaxf(sqrtf(s_ss[nl]), 1e-12f);
        #pragma unroll
        for (int mt = 0; mt < 4; ++mt) {
            #pragma unroll
            for (int r = 0; r < 4; ++r) {
                int m = mt * 16 + quad * 4 + r;
                out[(size_t)m * N + n] = acc[mt][nt][r] * inv;
            }
        }
    }
}

// ---------------- K3: per (row, chunk) partial top-10 ----------------
__global__ __launch_bounds__(256) void topk_part(
    const float* __restrict__ scores, float* __restrict__ cs, int* __restrict__ ci, int N) {
    const int b = blockIdx.y;
    const int c = blockIdx.x;
    const int t = threadIdx.x;
    const int chunk = (N + CH - 1) / CH;
    const int base  = c * chunk;
    const float* row = scores + (size_t)b * N;

    float ts[TOPK]; int ti[TOPK];
    #pragma unroll
    for (int j = 0; j < TOPK; ++j) { ts[j] = -3.4e38f; ti[j] = 0x7fffffff; }

    for (int e = t; e < chunk; e += 256) {
        int n = base + e;
        if (n >= N) break;
        float v = row[n];
        if (v > ts[TOPK - 1]) {                 // strict >: first-seen (lower idx) wins ties
            float cv = v; int cidx = n;
            #pragma unroll
            for (int j = 0; j < TOPK; ++j) {    // bubble into sorted-desc list (static indices only)
                bool g = (cv > ts[j]);
                float ns = g ? cv : ts[j]; int ni = g ? cidx : ti[j];
                cv = g ? ts[j] : cv; cidx = g ? ti[j] : cidx;
                ts[j] = ns; ti[j] = ni;
            }
        }
    }

    // spill sorted lists to LDS (dynamic 'ptr' indexing must not touch registers)
    __shared__ float all_s[256][TOPK];
    __shared__ int   all_i[256][TOPK];
    #pragma unroll
    for (int j = 0; j < TOPK; ++j) { all_s[t][j] = ts[j]; all_i[t][j] = ti[j]; }

    __shared__ float rs[256]; __shared__ int ri[256]; __shared__ int rt[256];
    int ptr = 0;
    __syncthreads();

    for (int round = 0; round < TOPK; ++round) {
        rs[t] = (ptr < TOPK) ? all_s[t][ptr] : -3.4e38f;
        ri[t] = (ptr < TOPK) ? all_i[t][ptr] : 0x7fffffff;
        rt[t] = t;
        __syncthreads();
        for (int s = 128; s > 0; s >>= 1) {
            if (t < s) {
                bool take = (rs[t + s] > rs[t]) ||
                            (rs[t + s] == rs[t] && ri[t + s] < ri[t]);
                if (take) { rs[t] = rs[t + s]; ri[t] = ri[t + s]; rt[t] = rt[t + s]; }
            }
            __syncthreads();
        }
        if (t == 0) {
            cs[((size_t)b * CH + c) * TOPK + round] = rs[0];
            ci[((size_t)b * CH + c) * TOPK + round] = ri[0];
        }
        if (t == rt[0]) ++ptr;                  // winner advances its head
        __syncthreads();                        // protect rs/rt from next round's writes
    }
}

// ---------------- K4: merge CH*10 candidates per row, write float(index) ----------------
__global__ void topk_final(const float* __restrict__ cs, const int* __restrict__ ci,
                           float* __restrict__ outIdx) {
    const int b = blockIdx.x;
    const int t = threadIdx.x;                  // 64 threads
    __shared__ float fs[CH * TOPK];
    __shared__ int   fi[CH * TOPK];
    for (int j = t; j < CH * TOPK; j += 64) {
        fs[j] = cs[(size_t)b * CH * TOPK + j];
        fi[j] = ci[(size_t)b * CH * TOPK + j];
    }
    __syncthreads();
    if (t == 0) {
        float ts[TOPK]; int ti[TOPK];
        #pragma unroll
        for (int j = 0; j < TOPK; ++j) { ts[j] = -3.4e38f; ti[j] = 0x7fffffff; }
        for (int e = 0; e < CH * TOPK; ++e) {
            float cv = fs[e]; int cidx = fi[e];
            if (cv > ts[TOPK - 1] || (cv == ts[TOPK - 1] && cidx < ti[TOPK - 1])) {
                #pragma unroll
                for (int j = 0; j < TOPK; ++j) {
                    bool g = (cv > ts[j]) || (cv == ts[j] && cidx < ti[j]);
                    float ns = g ? cv : ts[j]; int ni = g ? cidx : ti[j];
                    cv = g ? ts[j] : cv; cidx = g ? ti[j] : cidx;
                    ts[j] = ns; ti[j] = ni;
                }
            }
        }
        #pragma unroll
        for (int j = 0; j < TOPK; ++j) outIdx[b * TOPK + j] = (float)ti[j];
    }
}

extern "C" void kernel_launch(void* const* d_in, const int* in_sizes, int n_in,
                              void* d_out, int out_size, void* d_ws, size_t ws_size,
                              hipStream_t stream) {
    const float* T = (const float*)d_in[0];
    const float* S = (const float*)d_in[1];
    const int N = in_sizes[1] / D_DIM;          // 500000
    float* out = (float*)d_out;

    // ws layout: tHi[64*512]u16 | tLo[64*512]u16 | cand scores[64*CH*10]f32 | cand idx[64*CH*10]i32
    unsigned short* tHi = (unsigned short*)d_ws;
    unsigned short* tLo = tHi + B_TEXT * D_DIM;
    float* cs = (float*)(tLo + B_TEXT * D_DIM);
    int*   ci = (int*)(cs + B_TEXT * CH * TOPK);

    prep_text<<<B_TEXT, 64, 0, stream>>>(T, tHi, tLo);
    int nblk = (N + TILE_N - 1) / TILE_N;
    gemm_scores<<<nblk, 256, 0, stream>>>(S, tHi, tLo, out, N);
    dim3 g3(CH, B_TEXT);
    topk_part<<<g3, 256, 0, stream>>>(out, cs, ci, N);
    topk_final<<<B_TEXT, 64, 0, stream>>>(cs, ci, out + (size_t)B_TEXT * N);
}